// Round 3
// baseline (257.042 us; speedup 1.0000x reference)
//
#include <hip/hip_runtime.h>

// ---------------------------------------------------------------------------
// CrossModeAttention: B=4, N=1024, D1=D2=512, C=512, H=8, DH=64, LAYERS=3
// Pipeline: convert->bf16, fused QKV projection (MFMA), per-layer
// flash-attention (MFMA) + residual LayerNorm, V re-projected each layer.
// ---------------------------------------------------------------------------

#define LOG2E 1.44269504088896f

using f32x4   = __attribute__((ext_vector_type(4))) float;
using short8  = __attribute__((ext_vector_type(8))) short;
using ushort8 = __attribute__((ext_vector_type(8))) unsigned short;

__device__ inline unsigned short f2bf(float f) {
  unsigned u = __builtin_bit_cast(unsigned, f);
  u += 0x7fffu + ((u >> 16) & 1u);   // RNE
  return (unsigned short)(u >> 16);
}

__device__ inline f32x4 mfma_bf16(short8 a, short8 b, f32x4 c) {
  return __builtin_amdgcn_mfma_f32_16x16x32_bf16(a, b, c, 0, 0, 0);
}

// XOR swizzle for 128B-row LDS tiles (G4): spreads the 16B slots of a column
// across banks within each 8-row stripe.
__device__ inline int swz(int row, int byte_in_row) {
  return row * 128 + (byte_in_row ^ ((row & 7) << 4));
}

// ---------------------------------------------------------------------------
// Convert x1|x2 (f32) -> xb bf16 [4096][1024]
// ---------------------------------------------------------------------------
__global__ __launch_bounds__(256) void k_convert_x(
    const float* __restrict__ x1, const float* __restrict__ x2,
    unsigned short* __restrict__ xb) {
  int i  = blockIdx.x * 256 + threadIdx.x;  // one per 8 elements
  int e0 = i * 8;
  int m  = e0 >> 10;
  int d  = e0 & 1023;
  const float* src = (d < 512) ? (x1 + (size_t)m * 512 + d)
                               : (x2 + (size_t)m * 512 + (d - 512));
  float4 a = ((const float4*)src)[0];
  float4 b = ((const float4*)src)[1];
  ushort8 o;
  o[0] = f2bf(a.x); o[1] = f2bf(a.y); o[2] = f2bf(a.z); o[3] = f2bf(a.w);
  o[4] = f2bf(b.x); o[5] = f2bf(b.y); o[6] = f2bf(b.z); o[7] = f2bf(b.w);
  *(ushort8*)(xb + (size_t)e0) = o;
}

// Generic f32 -> bf16 (weights)
__global__ __launch_bounds__(256) void k_convert(
    const float* __restrict__ in, unsigned short* __restrict__ out, int n8) {
  int i = blockIdx.x * 256 + threadIdx.x;
  if (i >= n8) return;
  const float4* p = (const float4*)(in + (size_t)i * 8);
  float4 a = p[0], b = p[1];
  ushort8 o;
  o[0] = f2bf(a.x); o[1] = f2bf(a.y); o[2] = f2bf(a.z); o[3] = f2bf(a.w);
  o[4] = f2bf(b.x); o[5] = f2bf(b.y); o[6] = f2bf(b.z); o[7] = f2bf(b.w);
  *(ushort8*)(out + (size_t)i * 8) = o;
}

// ---------------------------------------------------------------------------
// Projections: z=0 Q (x1 part, K=512), z=1 K (x2 part, K=512), z=2 V (K=1024)
// C[m,c] = sum_k A[m,k] * W[c,k].  64x64 tile per block, 4 waves (16 rows ea).
// Q,K -> bf16 [B,H,N,64]; V -> f32 [B,N,512]
// ---------------------------------------------------------------------------
__global__ __launch_bounds__(256) void k_proj(
    const unsigned short* __restrict__ xb,
    const unsigned short* __restrict__ Wqb,
    const unsigned short* __restrict__ Wkb,
    const unsigned short* __restrict__ Wvb,
    unsigned short* __restrict__ Qb, unsigned short* __restrict__ Kb,
    float* __restrict__ Vf) {
  const int z  = blockIdx.z;
  const int c0 = blockIdx.x * 64;
  const int m0 = blockIdx.y * 64;
  const int w  = threadIdx.x >> 6;
  const int l  = threadIdx.x & 63;
  const int lr = l & 15, ls = l >> 4;

  const unsigned short* W = (z == 0) ? Wqb : (z == 1) ? Wkb : Wvb;
  const int K    = (z == 2) ? 1024 : 512;
  const int aoff = (z == 1) ? 512 : 0;

  const unsigned short* A  = xb + (size_t)(m0 + w * 16 + lr) * 1024 + aoff + ls * 8;
  const unsigned short* Bp = W + (size_t)(c0 + lr) * K + ls * 8;

  f32x4 acc[4] = {};
  for (int k = 0; k < K; k += 32) {
    short8 a = *(const short8*)(A + k);
#pragma unroll
    for (int nt = 0; nt < 4; ++nt) {
      short8 b = *(const short8*)(Bp + (size_t)nt * 16 * K + k);
      acc[nt] = mfma_bf16(a, b, acc[nt]);
    }
  }
#pragma unroll
  for (int nt = 0; nt < 4; ++nt) {
#pragma unroll
    for (int r = 0; r < 4; ++r) {
      int m = m0 + w * 16 + ls * 4 + r;   // C/D: row=(l>>4)*4+r, col=l&15
      int c = c0 + nt * 16 + lr;
      float v = acc[nt][r];
      if (z == 2) {
        Vf[(size_t)m * 512 + c] = v;
      } else {
        int b = m >> 10, n = m & 1023, h = c >> 6, dh = c & 63;
        size_t idx = ((size_t)(b * 8 + h) * 1024 + n) * 64 + dh;
        (z == 0 ? Qb : Kb)[idx] = f2bf(v);
      }
    }
  }
}

// ---------------------------------------------------------------------------
// Transpose: Vf f32 [B,N,512] -> Vt bf16 [B,H,64,N]  (per-head [DH,N])
// ---------------------------------------------------------------------------
__global__ __launch_bounds__(256) void k_transpose_v(
    const float* __restrict__ Vf, unsigned short* __restrict__ Vt) {
  __shared__ unsigned short tile[64 * 66];   // stride 66 elems = 132B (odd dwords)
  const int bh = blockIdx.y;                 // 0..31
  const int b = bh >> 3, h = bh & 7;
  const int n0 = blockIdx.x * 64;
  const int t = threadIdx.x;
  {
    int n = t >> 2, dh0 = (t & 3) * 16;
    const float* src = Vf + ((size_t)b * 1024 + n0 + n) * 512 + h * 64 + dh0;
    unsigned short* dst = tile + n * 66 + dh0;
#pragma unroll
    for (int j = 0; j < 16; j += 4) {
      float4 v = *(const float4*)(src + j);
      dst[j + 0] = f2bf(v.x); dst[j + 1] = f2bf(v.y);
      dst[j + 2] = f2bf(v.z); dst[j + 3] = f2bf(v.w);
    }
  }
  __syncthreads();
#pragma unroll
  for (int it = 0; it < 2; ++it) {
    int dh = (t >> 3) + it * 32, n8 = (t & 7) * 8;
    ushort8 o;
#pragma unroll
    for (int j = 0; j < 8; ++j) o[j] = tile[(n8 + j) * 66 + dh];
    *(ushort8*)(Vt + ((size_t)(bh * 64 + dh)) * 1024 + n0 + n8) = o;
  }
}

// ---------------------------------------------------------------------------
// Flash attention, one (b,h), 64 q-rows per block, 4 waves x 16 rows.
// K chunk [64 kidx][64 dh], V chunk [64 dh][64 kidx] staged in LDS (swizzled).
// Reference mask semantics: score==0 -> excluded (p=0); all-masked row -> 0.
// Writes V1 f32 [B,N,512].
// ---------------------------------------------------------------------------
__global__ __launch_bounds__(256) void k_attn(
    const unsigned short* __restrict__ Qb,
    const unsigned short* __restrict__ Kb,
    const unsigned short* __restrict__ Vt,
    float* __restrict__ V1) {
  __shared__ char lds[8192 + 8192 + 4 * 16 * 144];
  char* kbuf = lds;
  char* vbuf = lds + 8192;
  const int bh = blockIdx.y;
  const int q0 = blockIdx.x * 64;
  const int t = threadIdx.x;
  const int w = t >> 6, l = t & 63, lr = l & 15, ls = l >> 4;
  char* pbuf = lds + 16384 + w * (16 * 144);

  const float scale = 0.044194173824159216f;   // 512^-0.5

  short8 qa[2];
  {
    const unsigned short* Qg =
        Qb + ((size_t)bh * 1024 + q0 + w * 16 + lr) * 64 + ls * 8;
    qa[0] = *(const short8*)(Qg);
    qa[1] = *(const short8*)(Qg + 32);
  }

  f32x4 O[4] = {};
  float mrow[4], lrow[4];
#pragma unroll
  for (int r = 0; r < 4; ++r) { mrow[r] = -INFINITY; lrow[r] = 0.f; }

  const unsigned short* Kg = Kb + (size_t)bh * 1024 * 64;
  const unsigned short* Vg = Vt + (size_t)bh * 64 * 1024;

  for (int kc = 0; kc < 16; ++kc) {
    {
      int row = t >> 3;          // 0..31
      int c8  = (t & 7) * 8;     // element offset within row
#pragma unroll
      for (int it = 0; it < 2; ++it) {
        int rr = row + it * 32;
        int4 kv = *(const int4*)(Kg + (size_t)(kc * 64 + rr) * 64 + c8);
        *(int4*)(kbuf + swz(rr, c8 * 2)) = kv;
        int4 vv = *(const int4*)(Vg + (size_t)rr * 1024 + kc * 64 + c8);
        *(int4*)(vbuf + swz(rr, c8 * 2)) = vv;
      }
    }
    __syncthreads();

    // S = Q K^T  (K-dim = dh, 2 steps of 32)
    f32x4 s[4] = {};
#pragma unroll
    for (int kk = 0; kk < 2; ++kk) {
#pragma unroll
      for (int nt = 0; nt < 4; ++nt) {
        short8 bk = *(const short8*)(kbuf + swz(nt * 16 + lr, kk * 64 + ls * 16));
        s[nt] = mfma_bf16(qa[kk], bk, s[nt]);
      }
    }

    // online softmax (rows = ls*4+r, cols spread over 16 lanes x 4 nt)
    float p[4][4];
    float cmax[4];
#pragma unroll
    for (int r = 0; r < 4; ++r) cmax[r] = -INFINITY;
#pragma unroll
    for (int nt = 0; nt < 4; ++nt)
#pragma unroll
      for (int r = 0; r < 4; ++r) {
        float sv = s[nt][r];
        p[nt][r] = (sv == 0.f) ? -INFINITY : sv * scale;   // masked score
        cmax[r] = fmaxf(cmax[r], p[nt][r]);
      }
#pragma unroll
    for (int r = 0; r < 4; ++r)
#pragma unroll
      for (int off = 1; off < 16; off <<= 1)
        cmax[r] = fmaxf(cmax[r], __shfl_xor(cmax[r], off, 64));

    float alpha[4];
#pragma unroll
    for (int r = 0; r < 4; ++r) {
      float mnew = fmaxf(mrow[r], cmax[r]);
      alpha[r] = (mnew == -INFINITY) ? 1.f
                                     : exp2f((mrow[r] - mnew) * LOG2E);
      mrow[r] = mnew;
    }
    float lsum[4] = {0.f, 0.f, 0.f, 0.f};
#pragma unroll
    for (int nt = 0; nt < 4; ++nt)
#pragma unroll
      for (int r = 0; r < 4; ++r) {
        float pv = (p[nt][r] == -INFINITY)
                       ? 0.f
                       : exp2f((p[nt][r] - mrow[r]) * LOG2E);
        p[nt][r] = pv;
        lsum[r] += pv;
      }
#pragma unroll
    for (int r = 0; r < 4; ++r) {
#pragma unroll
      for (int off = 1; off < 16; off <<= 1)
        lsum[r] += __shfl_xor(lsum[r], off, 64);
      lrow[r] = lrow[r] * alpha[r] + lsum[r];
    }
#pragma unroll
    for (int dt = 0; dt < 4; ++dt)
#pragma unroll
      for (int r = 0; r < 4; ++r) O[dt][r] *= alpha[r];

    // P accumulator-layout -> A-fragment layout via per-wave LDS
#pragma unroll
    for (int nt = 0; nt < 4; ++nt)
#pragma unroll
      for (int r = 0; r < 4; ++r)
        *(unsigned short*)(pbuf + (ls * 4 + r) * 144 + (nt * 16 + lr) * 2) =
            f2bf(p[nt][r]);

    // O += P V  (K-dim = kidx, 2 steps of 32)
#pragma unroll
    for (int kk = 0; kk < 2; ++kk) {
      short8 pa = *(const short8*)(pbuf + lr * 144 + kk * 64 + ls * 16);
#pragma unroll
      for (int dt = 0; dt < 4; ++dt) {
        short8 bv = *(const short8*)(vbuf + swz(dt * 16 + lr, kk * 64 + ls * 16));
        O[dt] = mfma_bf16(pa, bv, O[dt]);
      }
    }
    __syncthreads();
  }

  float rinv[4];
#pragma unroll
  for (int r = 0; r < 4; ++r) rinv[r] = (lrow[r] > 0.f) ? 1.f / lrow[r] : 0.f;
  const int b = bh >> 3, h = bh & 7;
#pragma unroll
  for (int dt = 0; dt < 4; ++dt)
#pragma unroll
    for (int r = 0; r < 4; ++r) {
      int n = q0 + w * 16 + ls * 4 + r;
      int c = h * 64 + dt * 16 + lr;
      V1[((size_t)b * 1024 + n) * 512 + c] = O[dt][r] * rinv[r];
    }
}

// ---------------------------------------------------------------------------
// LayerNorm over C=512 of (V1 + Vf); writes outp (Vf for layers 0/1, d_out last)
// ---------------------------------------------------------------------------
__global__ __launch_bounds__(256) void k_ln(
    const float* __restrict__ V1, const float* __restrict__ Vf_in,
    const float* __restrict__ gamma, const float* __restrict__ beta,
    float* __restrict__ outp) {
  const int row = blockIdx.x;   // 0..4095
  const int t = threadIdx.x;
  const float* a = V1 + (size_t)row * 512;
  const float* b = Vf_in + (size_t)row * 512;
  float x0 = a[t] + b[t];
  float x1 = a[t + 256] + b[t + 256];
  float s  = x0 + x1;
  float sq = x0 * x0 + x1 * x1;
#pragma unroll
  for (int off = 32; off >= 1; off >>= 1) {
    s  += __shfl_down(s, off, 64);
    sq += __shfl_down(sq, off, 64);
  }
  __shared__ float red[8];
  int w = t >> 6, l = t & 63;
  if (l == 0) { red[w] = s; red[w + 4] = sq; }
  __syncthreads();
  s  = red[0] + red[1] + red[2] + red[3];
  sq = red[4] + red[5] + red[6] + red[7];
  float mu   = s * (1.f / 512.f);
  float var  = sq * (1.f / 512.f) - mu * mu;
  float rstd = rsqrtf(var + 1e-5f);
  float y0 = (x0 - mu) * rstd * gamma[t] + beta[t];
  float y1 = (x1 - mu) * rstd * gamma[t + 256] + beta[t + 256];
  outp[(size_t)row * 512 + t] = y0;
  outp[(size_t)row * 512 + t + 256] = y1;
}

// ---------------------------------------------------------------------------
extern "C" void kernel_launch(void* const* d_in, const int* in_sizes, int n_in,
                              void* d_out, int out_size, void* d_ws,
                              size_t ws_size, hipStream_t stream) {
  const float* x1    = (const float*)d_in[0];
  const float* x2    = (const float*)d_in[1];
  const float* Wq    = (const float*)d_in[2];
  const float* Wk    = (const float*)d_in[3];
  const float* Wv    = (const float*)d_in[4];
  const float* gamma = (const float*)d_in[5];
  const float* beta  = (const float*)d_in[6];
  float* out = (float*)d_out;
  char* ws = (char*)d_ws;

  const size_t MB = 1u << 20;
  unsigned short* xb  = (unsigned short*)(ws);                 // 8 MB
  unsigned short* Wqb = (unsigned short*)(ws + 8 * MB);        // 0.5 MB
  unsigned short* Wkb = (unsigned short*)(ws + 8 * MB + 512 * 1024);
  unsigned short* Wvb = (unsigned short*)(ws + 9 * MB);        // 1 MB
  unsigned short* Qb  = (unsigned short*)(ws + 10 * MB);       // 4 MB
  unsigned short* Kb  = (unsigned short*)(ws + 14 * MB);       // 4 MB
  unsigned short* Vt  = (unsigned short*)(ws + 18 * MB);       // 4 MB
  float*          Vf  = (float*)(ws + 22 * MB);                // 8 MB
  float*          V1  = (float*)(ws + 30 * MB);                // 8 MB

  k_convert_x<<<2048, 256, 0, stream>>>(x1, x2, xb);
  k_convert<<<128, 256, 0, stream>>>(Wq, Wqb, 32768);
  k_convert<<<128, 256, 0, stream>>>(Wk, Wkb, 32768);
  k_convert<<<256, 256, 0, stream>>>(Wv, Wvb, 65536);

  k_proj<<<dim3(8, 64, 3), 256, 0, stream>>>(xb, Wqb, Wkb, Wvb, Qb, Kb, Vf);
  k_transpose_v<<<dim3(16, 32), 256, 0, stream>>>(Vf, Vt);

  for (int layer = 0; layer < 3; ++layer) {
    k_attn<<<dim3(16, 32), 256, 0, stream>>>(Qb, Kb, Vt, V1);
    k_ln<<<4096, 256, 0, stream>>>(V1, Vf, gamma, beta,
                                   (layer == 2) ? out : Vf);
    if (layer < 2) k_transpose_v<<<dim3(16, 32), 256, 0, stream>>>(Vf, Vt);
  }
}

// Round 4
// 209.103 us; speedup vs baseline: 1.2293x; 1.2293x over previous
//
#include <hip/hip_runtime.h>

// ---------------------------------------------------------------------------
// CrossModeAttention: B=4, N=1024, D1=D2=512, C=512, H=8, DH=64, LAYERS=3
// Pipeline: convert->bf16, fused QKV projection (MFMA, 128x128 LDS-staged),
// per-layer flash-attention (MFMA) + residual LayerNorm.
// ---------------------------------------------------------------------------

#define LOG2E 1.44269504088896f

using f32x4   = __attribute__((ext_vector_type(4))) float;
using short8  = __attribute__((ext_vector_type(8))) short;
using ushort8 = __attribute__((ext_vector_type(8))) unsigned short;

__device__ inline unsigned short f2bf(float f) {
  unsigned u = __builtin_bit_cast(unsigned, f);
  u += 0x7fffu + ((u >> 16) & 1u);   // RNE
  return (unsigned short)(u >> 16);
}

__device__ inline f32x4 mfma_bf16(short8 a, short8 b, f32x4 c) {
  return __builtin_amdgcn_mfma_f32_16x16x32_bf16(a, b, c, 0, 0, 0);
}

// async global->LDS, 16B per lane; LDS dest = wave-uniform base + lane*16
__device__ inline void gload_lds16(const void* g, void* l) {
  __builtin_amdgcn_global_load_lds(
      (const __attribute__((address_space(1))) unsigned int*)g,
      (__attribute__((address_space(3))) unsigned int*)l, 16, 0, 0);
}

// XOR swizzle for 128B-row LDS tiles (G4) — used by k_attn
__device__ inline int swz(int row, int byte_in_row) {
  return row * 128 + (byte_in_row ^ ((row & 7) << 4));
}

// ---------------------------------------------------------------------------
// Convert x1|x2 (f32) -> xb bf16 [4096][1024]
// ---------------------------------------------------------------------------
__global__ __launch_bounds__(256) void k_convert_x(
    const float* __restrict__ x1, const float* __restrict__ x2,
    unsigned short* __restrict__ xb) {
  int i  = blockIdx.x * 256 + threadIdx.x;
  int e0 = i * 8;
  int m  = e0 >> 10;
  int d  = e0 & 1023;
  const float* src = (d < 512) ? (x1 + (size_t)m * 512 + d)
                               : (x2 + (size_t)m * 512 + (d - 512));
  float4 a = ((const float4*)src)[0];
  float4 b = ((const float4*)src)[1];
  ushort8 o;
  o[0] = f2bf(a.x); o[1] = f2bf(a.y); o[2] = f2bf(a.z); o[3] = f2bf(a.w);
  o[4] = f2bf(b.x); o[5] = f2bf(b.y); o[6] = f2bf(b.z); o[7] = f2bf(b.w);
  *(ushort8*)(xb + (size_t)e0) = o;
}

// Generic f32 -> bf16 (weights)
__global__ __launch_bounds__(256) void k_convert(
    const float* __restrict__ in, unsigned short* __restrict__ out, int n8) {
  int i = blockIdx.x * 256 + threadIdx.x;
  if (i >= n8) return;
  const float4* p = (const float4*)(in + (size_t)i * 8);
  float4 a = p[0], b = p[1];
  ushort8 o;
  o[0] = f2bf(a.x); o[1] = f2bf(a.y); o[2] = f2bf(a.z); o[3] = f2bf(a.w);
  o[4] = f2bf(b.x); o[5] = f2bf(b.y); o[6] = f2bf(b.z); o[7] = f2bf(b.w);
  *(ushort8*)(out + (size_t)i * 8) = o;
}

// ---------------------------------------------------------------------------
// Projections v2: m97-structure GEMM. 128x128 tile, BK=64, global_load_lds
// staging, 4 waves x 64x64 quadrant (4x4 frags of 16x16x32).
// z=0 Q (x1 cols, K=512), z=1 K (x2 cols, K=512), z=2 V (K=1024).
// C[m,c] = sum_k A[m,k]*W[c,k].  Q,K -> bf16 [B,H,N,64]; V -> f32 [B,N,512].
// Grid: 384 blocks 1-D, z = id%3 (round-robin so V's 2x-K blocks spread
// evenly across XCDs).
// ---------------------------------------------------------------------------
__global__ __launch_bounds__(256) void k_proj(
    const unsigned short* __restrict__ xb,
    const unsigned short* __restrict__ Wqb,
    const unsigned short* __restrict__ Wkb,
    const unsigned short* __restrict__ Wvb,
    unsigned short* __restrict__ Qb, unsigned short* __restrict__ Kb,
    float* __restrict__ Vf) {
  __shared__ __align__(16) unsigned short Atile[128 * 64];  // 16 KB
  __shared__ __align__(16) unsigned short Btile[128 * 64];  // 16 KB

  const int id  = blockIdx.x;
  const int z   = id % 3;
  const int rem = id / 3;             // 0..127
  const int c0  = (rem & 3) * 128;    // 4 n-blocks
  const int m0  = (rem >> 2) * 128;   // 32 m-blocks

  const int K    = (z == 2) ? 1024 : 512;
  const int aoff = (z == 1) ? 512 : 0;
  const unsigned short* W = (z == 0) ? Wqb : (z == 1) ? Wkb : Wvb;

  const int t  = threadIdx.x;
  const int w  = t >> 6, l = t & 63;
  const int lr = l & 15, ls = l >> 4;
  const int wr = w >> 1, wc = w & 1;       // wave quadrant

  // staging: wave w covers chunks w*4..w*4+3; chunk = 8 rows x 64 cols (1 KB)
  const int srow  = l >> 3;                // row within chunk
  const int scol8 = (l & 7) * 8;           // element col offset (16B chunks)

  f32x4 acc[4][4] = {};

  for (int k0 = 0; k0 < K; k0 += 64) {
#pragma unroll
    for (int j = 0; j < 4; ++j) {
      int ch  = w * 4 + j;
      int row = ch * 8 + srow;
      gload_lds16(xb + (size_t)(m0 + row) * 1024 + aoff + k0 + scol8,
                  Atile + ch * 512);
      gload_lds16(W + (size_t)(c0 + row) * K + k0 + scol8,
                  Btile + ch * 512);
    }
    __syncthreads();   // drains vmcnt (gload_lds) + barrier
#pragma unroll
    for (int ks = 0; ks < 2; ++ks) {
      short8 af[4], bf[4];
#pragma unroll
      for (int mf = 0; mf < 4; ++mf)
        af[mf] = *(const short8*)(Atile + (wr * 64 + mf * 16 + lr) * 64 +
                                  ks * 32 + ls * 8);
#pragma unroll
      for (int nf = 0; nf < 4; ++nf)
        bf[nf] = *(const short8*)(Btile + (wc * 64 + nf * 16 + lr) * 64 +
                                  ks * 32 + ls * 8);
#pragma unroll
      for (int mf = 0; mf < 4; ++mf)
#pragma unroll
        for (int nf = 0; nf < 4; ++nf)
          acc[mf][nf] = mfma_bf16(af[mf], bf[nf], acc[mf][nf]);
    }
    __syncthreads();
  }

#pragma unroll
  for (int mf = 0; mf < 4; ++mf)
#pragma unroll
    for (int nf = 0; nf < 4; ++nf)
#pragma unroll
      for (int r = 0; r < 4; ++r) {
        int m = m0 + wr * 64 + mf * 16 + ls * 4 + r;  // C/D: row=(l>>4)*4+r
        int c = c0 + wc * 64 + nf * 16 + lr;          //      col=l&15
        float v = acc[mf][nf][r];
        if (z == 2) {
          Vf[(size_t)m * 512 + c] = v;
        } else {
          int b = m >> 10, n = m & 1023, h = c >> 6, dh = c & 63;
          size_t idx = ((size_t)(b * 8 + h) * 1024 + n) * 64 + dh;
          (z == 0 ? Qb : Kb)[idx] = f2bf(v);
        }
      }
}

// ---------------------------------------------------------------------------
// Transpose: Vf f32 [B,N,512] -> Vt bf16 [B,H,64,N]  (per-head [DH,N])
// ---------------------------------------------------------------------------
__global__ __launch_bounds__(256) void k_transpose_v(
    const float* __restrict__ Vf, unsigned short* __restrict__ Vt) {
  __shared__ unsigned short tile[64 * 66];
  const int bh = blockIdx.y;
  const int b = bh >> 3, h = bh & 7;
  const int n0 = blockIdx.x * 64;
  const int t = threadIdx.x;
  {
    int n = t >> 2, dh0 = (t & 3) * 16;
    const float* src = Vf + ((size_t)b * 1024 + n0 + n) * 512 + h * 64 + dh0;
    unsigned short* dst = tile + n * 66 + dh0;
#pragma unroll
    for (int j = 0; j < 16; j += 4) {
      float4 v = *(const float4*)(src + j);
      dst[j + 0] = f2bf(v.x); dst[j + 1] = f2bf(v.y);
      dst[j + 2] = f2bf(v.z); dst[j + 3] = f2bf(v.w);
    }
  }
  __syncthreads();
#pragma unroll
  for (int it = 0; it < 2; ++it) {
    int dh = (t >> 3) + it * 32, n8 = (t & 7) * 8;
    ushort8 o;
#pragma unroll
    for (int j = 0; j < 8; ++j) o[j] = tile[(n8 + j) * 66 + dh];
    *(ushort8*)(Vt + ((size_t)(bh * 64 + dh)) * 1024 + n0 + n8) = o;
  }
}

// ---------------------------------------------------------------------------
// Flash attention, one (b,h), 64 q-rows per block, 4 waves x 16 rows.
// ---------------------------------------------------------------------------
__global__ __launch_bounds__(256) void k_attn(
    const unsigned short* __restrict__ Qb,
    const unsigned short* __restrict__ Kb,
    const unsigned short* __restrict__ Vt,
    float* __restrict__ V1) {
  __shared__ char lds[8192 + 8192 + 4 * 16 * 144];
  char* kbuf = lds;
  char* vbuf = lds + 8192;
  const int bh = blockIdx.y;
  const int q0 = blockIdx.x * 64;
  const int t = threadIdx.x;
  const int w = t >> 6, l = t & 63, lr = l & 15, ls = l >> 4;
  char* pbuf = lds + 16384 + w * (16 * 144);

  const float scale = 0.044194173824159216f;   // 512^-0.5

  short8 qa[2];
  {
    const unsigned short* Qg =
        Qb + ((size_t)bh * 1024 + q0 + w * 16 + lr) * 64 + ls * 8;
    qa[0] = *(const short8*)(Qg);
    qa[1] = *(const short8*)(Qg + 32);
  }

  f32x4 O[4] = {};
  float mrow[4], lrow[4];
#pragma unroll
  for (int r = 0; r < 4; ++r) { mrow[r] = -INFINITY; lrow[r] = 0.f; }

  const unsigned short* Kg = Kb + (size_t)bh * 1024 * 64;
  const unsigned short* Vg = Vt + (size_t)bh * 64 * 1024;

  for (int kc = 0; kc < 16; ++kc) {
    {
      int row = t >> 3;
      int c8  = (t & 7) * 8;
#pragma unroll
      for (int it = 0; it < 2; ++it) {
        int rr = row + it * 32;
        int4 kv = *(const int4*)(Kg + (size_t)(kc * 64 + rr) * 64 + c8);
        *(int4*)(kbuf + swz(rr, c8 * 2)) = kv;
        int4 vv = *(const int4*)(Vg + (size_t)rr * 1024 + kc * 64 + c8);
        *(int4*)(vbuf + swz(rr, c8 * 2)) = vv;
      }
    }
    __syncthreads();

    f32x4 s[4] = {};
#pragma unroll
    for (int kk = 0; kk < 2; ++kk) {
#pragma unroll
      for (int nt = 0; nt < 4; ++nt) {
        short8 bk = *(const short8*)(kbuf + swz(nt * 16 + lr, kk * 64 + ls * 16));
        s[nt] = mfma_bf16(qa[kk], bk, s[nt]);
      }
    }

    float p[4][4];
    float cmax[4];
#pragma unroll
    for (int r = 0; r < 4; ++r) cmax[r] = -INFINITY;
#pragma unroll
    for (int nt = 0; nt < 4; ++nt)
#pragma unroll
      for (int r = 0; r < 4; ++r) {
        float sv = s[nt][r];
        p[nt][r] = (sv == 0.f) ? -INFINITY : sv * scale;
        cmax[r] = fmaxf(cmax[r], p[nt][r]);
      }
#pragma unroll
    for (int r = 0; r < 4; ++r)
#pragma unroll
      for (int off = 1; off < 16; off <<= 1)
        cmax[r] = fmaxf(cmax[r], __shfl_xor(cmax[r], off, 64));

    float alpha[4];
#pragma unroll
    for (int r = 0; r < 4; ++r) {
      float mnew = fmaxf(mrow[r], cmax[r]);
      alpha[r] = (mnew == -INFINITY) ? 1.f
                                     : exp2f((mrow[r] - mnew) * LOG2E);
      mrow[r] = mnew;
    }
    float lsum[4] = {0.f, 0.f, 0.f, 0.f};
#pragma unroll
    for (int nt = 0; nt < 4; ++nt)
#pragma unroll
      for (int r = 0; r < 4; ++r) {
        float pv = (p[nt][r] == -INFINITY)
                       ? 0.f
                       : exp2f((p[nt][r] - mrow[r]) * LOG2E);
        p[nt][r] = pv;
        lsum[r] += pv;
      }
#pragma unroll
    for (int r = 0; r < 4; ++r) {
#pragma unroll
      for (int off = 1; off < 16; off <<= 1)
        lsum[r] += __shfl_xor(lsum[r], off, 64);
      lrow[r] = lrow[r] * alpha[r] + lsum[r];
    }
#pragma unroll
    for (int dt = 0; dt < 4; ++dt)
#pragma unroll
      for (int r = 0; r < 4; ++r) O[dt][r] *= alpha[r];

#pragma unroll
    for (int nt = 0; nt < 4; ++nt)
#pragma unroll
      for (int r = 0; r < 4; ++r)
        *(unsigned short*)(pbuf + (ls * 4 + r) * 144 + (nt * 16 + lr) * 2) =
            f2bf(p[nt][r]);

#pragma unroll
    for (int kk = 0; kk < 2; ++kk) {
      short8 pa = *(const short8*)(pbuf + lr * 144 + kk * 64 + ls * 16);
#pragma unroll
      for (int dt = 0; dt < 4; ++dt) {
        short8 bv = *(const short8*)(vbuf + swz(dt * 16 + lr, kk * 64 + ls * 16));
        O[dt] = mfma_bf16(pa, bv, O[dt]);
      }
    }
    __syncthreads();
  }

  float rinv[4];
#pragma unroll
  for (int r = 0; r < 4; ++r) rinv[r] = (lrow[r] > 0.f) ? 1.f / lrow[r] : 0.f;
  const int b = bh >> 3, h = bh & 7;
#pragma unroll
  for (int dt = 0; dt < 4; ++dt)
#pragma unroll
    for (int r = 0; r < 4; ++r) {
      int n = q0 + w * 16 + ls * 4 + r;
      int c = h * 64 + dt * 16 + lr;
      V1[((size_t)b * 1024 + n) * 512 + c] = O[dt][r] * rinv[r];
    }
}

// ---------------------------------------------------------------------------
// LayerNorm over C=512 of (V1 + Vf); writes outp (Vf for layers 0/1, d_out last)
// ---------------------------------------------------------------------------
__global__ __launch_bounds__(256) void k_ln(
    const float* __restrict__ V1, const float* __restrict__ Vf_in,
    const float* __restrict__ gamma, const float* __restrict__ beta,
    float* __restrict__ outp) {
  const int row = blockIdx.x;
  const int t = threadIdx.x;
  const float* a = V1 + (size_t)row * 512;
  const float* b = Vf_in + (size_t)row * 512;
  float x0 = a[t] + b[t];
  float x1 = a[t + 256] + b[t + 256];
  float s  = x0 + x1;
  float sq = x0 * x0 + x1 * x1;
#pragma unroll
  for (int off = 32; off >= 1; off >>= 1) {
    s  += __shfl_down(s, off, 64);
    sq += __shfl_down(sq, off, 64);
  }
  __shared__ float red[8];
  int w = t >> 6, l = t & 63;
  if (l == 0) { red[w] = s; red[w + 4] = sq; }
  __syncthreads();
  s  = red[0] + red[1] + red[2] + red[3];
  sq = red[4] + red[5] + red[6] + red[7];
  float mu   = s * (1.f / 512.f);
  float var  = sq * (1.f / 512.f) - mu * mu;
  float rstd = rsqrtf(var + 1e-5f);
  float y0 = (x0 - mu) * rstd * gamma[t] + beta[t];
  float y1 = (x1 - mu) * rstd * gamma[t + 256] + beta[t + 256];
  outp[(size_t)row * 512 + t] = y0;
  outp[(size_t)row * 512 + t + 256] = y1;
}

// ---------------------------------------------------------------------------
extern "C" void kernel_launch(void* const* d_in, const int* in_sizes, int n_in,
                              void* d_out, int out_size, void* d_ws,
                              size_t ws_size, hipStream_t stream) {
  const float* x1    = (const float*)d_in[0];
  const float* x2    = (const float*)d_in[1];
  const float* Wq    = (const float*)d_in[2];
  const float* Wk    = (const float*)d_in[3];
  const float* Wv    = (const float*)d_in[4];
  const float* gamma = (const float*)d_in[5];
  const float* beta  = (const float*)d_in[6];
  float* out = (float*)d_out;
  char* ws = (char*)d_ws;

  const size_t MB = 1u << 20;
  unsigned short* xb  = (unsigned short*)(ws);                 // 8 MB
  unsigned short* Wqb = (unsigned short*)(ws + 8 * MB);        // 0.5 MB
  unsigned short* Wkb = (unsigned short*)(ws + 8 * MB + 512 * 1024);
  unsigned short* Wvb = (unsigned short*)(ws + 9 * MB);        // 1 MB
  unsigned short* Qb  = (unsigned short*)(ws + 10 * MB);       // 4 MB
  unsigned short* Kb  = (unsigned short*)(ws + 14 * MB);       // 4 MB
  unsigned short* Vt  = (unsigned short*)(ws + 18 * MB);       // 4 MB
  float*          Vf  = (float*)(ws + 22 * MB);                // 8 MB
  float*          V1  = (float*)(ws + 30 * MB);                // 8 MB

  k_convert_x<<<2048, 256, 0, stream>>>(x1, x2, xb);
  k_convert<<<128, 256, 0, stream>>>(Wq, Wqb, 32768);
  k_convert<<<128, 256, 0, stream>>>(Wk, Wkb, 32768);
  k_convert<<<256, 256, 0, stream>>>(Wv, Wvb, 65536);

  k_proj<<<384, 256, 0, stream>>>(xb, Wqb, Wkb, Wvb, Qb, Kb, Vf);
  k_transpose_v<<<dim3(16, 32), 256, 0, stream>>>(Vf, Vt);

  for (int layer = 0; layer < 3; ++layer) {
    k_attn<<<dim3(16, 32), 256, 0, stream>>>(Qb, Kb, Vt, V1);
    k_ln<<<4096, 256, 0, stream>>>(V1, Vf, gamma, beta,
                                   (layer == 2) ? out : Vf);
    if (layer < 2) k_transpose_v<<<dim3(16, 32), 256, 0, stream>>>(Vf, Vt);
  }
}

// Round 6
// 151.660 us; speedup vs baseline: 1.6949x; 1.3788x over previous
//
#include <hip/hip_runtime.h>

// ---------------------------------------------------------------------------
// CrossModeAttention: B=4, N=1024, D1=D2=512, C=512, H=8, DH=64, LAYERS=3
// Key insight: Q,K are layer-invariant => softmax(QK^T) computed ONCE,
// materialized as P (bf16, 64MB, pre-swizzled); each layer = P·V GEMM + LN.
// Falls back to fused flash-attn path if workspace < 103MB.
// ---------------------------------------------------------------------------

#define LOG2E 1.44269504088896f

using f32x4   = __attribute__((ext_vector_type(4))) float;
using short8  = __attribute__((ext_vector_type(8))) short;
using ushort8 = __attribute__((ext_vector_type(8))) unsigned short;

__device__ inline unsigned short f2bf(float f) {
  unsigned u = __builtin_bit_cast(unsigned, f);
  u += 0x7fffu + ((u >> 16) & 1u);   // RNE
  return (unsigned short)(u >> 16);
}

__device__ inline f32x4 mfma_bf16(short8 a, short8 b, f32x4 c) {
  return __builtin_amdgcn_mfma_f32_16x16x32_bf16(a, b, c, 0, 0, 0);
}

// async global->LDS, 16B per lane; LDS dest = wave-uniform base + lane*16
__device__ inline void gload_lds16(const void* g, void* l) {
  __builtin_amdgcn_global_load_lds(
      (const __attribute__((address_space(1))) unsigned int*)g,
      (__attribute__((address_space(3))) unsigned int*)l, 16, 0, 0);
}

// XOR swizzle for 128B-row LDS tiles (G4): spreads a column's 16B slots
// across banks within each 8-row stripe.
__device__ inline int swz(int row, int byte_in_row) {
  return row * 128 + (byte_in_row ^ ((row & 7) << 4));
}

// ---------------------------------------------------------------------------
// Convert x1|x2 (f32) -> xb bf16 [4096][1024]
// ---------------------------------------------------------------------------
__global__ __launch_bounds__(256) void k_convert_x(
    const float* __restrict__ x1, const float* __restrict__ x2,
    unsigned short* __restrict__ xb) {
  int i  = blockIdx.x * 256 + threadIdx.x;
  int e0 = i * 8;
  int m  = e0 >> 10;
  int d  = e0 & 1023;
  const float* src = (d < 512) ? (x1 + (size_t)m * 512 + d)
                               : (x2 + (size_t)m * 512 + (d - 512));
  float4 a = ((const float4*)src)[0];
  float4 b = ((const float4*)src)[1];
  ushort8 o;
  o[0] = f2bf(a.x); o[1] = f2bf(a.y); o[2] = f2bf(a.z); o[3] = f2bf(a.w);
  o[4] = f2bf(b.x); o[5] = f2bf(b.y); o[6] = f2bf(b.z); o[7] = f2bf(b.w);
  *(ushort8*)(xb + (size_t)e0) = o;
}

// Generic f32 -> bf16 (weights)
__global__ __launch_bounds__(256) void k_convert(
    const float* __restrict__ in, unsigned short* __restrict__ out, int n8) {
  int i = blockIdx.x * 256 + threadIdx.x;
  if (i >= n8) return;
  const float4* p = (const float4*)(in + (size_t)i * 8);
  float4 a = p[0], b = p[1];
  ushort8 o;
  o[0] = f2bf(a.x); o[1] = f2bf(a.y); o[2] = f2bf(a.z); o[3] = f2bf(a.w);
  o[4] = f2bf(b.x); o[5] = f2bf(b.y); o[6] = f2bf(b.z); o[7] = f2bf(b.w);
  *(ushort8*)(out + (size_t)i * 8) = o;
}

// ---------------------------------------------------------------------------
// Projections: m97-structure GEMM. 128x128 tile, BK=64, global_load_lds.
// z=0 Q (K=512), z=1 K (K=512), z=2 V (K=1024).
// ---------------------------------------------------------------------------
__global__ __launch_bounds__(256) void k_proj(
    const unsigned short* __restrict__ xb,
    const unsigned short* __restrict__ Wqb,
    const unsigned short* __restrict__ Wkb,
    const unsigned short* __restrict__ Wvb,
    unsigned short* __restrict__ Qb, unsigned short* __restrict__ Kb,
    float* __restrict__ Vf) {
  __shared__ __align__(16) unsigned short Atile[128 * 64];  // 16 KB
  __shared__ __align__(16) unsigned short Btile[128 * 64];  // 16 KB

  const int id  = blockIdx.x;
  const int z   = id % 3;
  const int rem = id / 3;
  const int c0  = (rem & 3) * 128;
  const int m0  = (rem >> 2) * 128;

  const int K    = (z == 2) ? 1024 : 512;
  const int aoff = (z == 1) ? 512 : 0;
  const unsigned short* W = (z == 0) ? Wqb : (z == 1) ? Wkb : Wvb;

  const int t  = threadIdx.x;
  const int w  = t >> 6, l = t & 63;
  const int lr = l & 15, ls = l >> 4;
  const int wr = w >> 1, wc = w & 1;

  const int srow  = l >> 3;
  const int scol8 = (l & 7) * 8;

  f32x4 acc[4][4] = {};

  for (int k0 = 0; k0 < K; k0 += 64) {
#pragma unroll
    for (int j = 0; j < 4; ++j) {
      int ch  = w * 4 + j;
      int row = ch * 8 + srow;
      gload_lds16(xb + (size_t)(m0 + row) * 1024 + aoff + k0 + scol8,
                  Atile + ch * 512);
      gload_lds16(W + (size_t)(c0 + row) * K + k0 + scol8,
                  Btile + ch * 512);
    }
    __syncthreads();
#pragma unroll
    for (int ks = 0; ks < 2; ++ks) {
      short8 af[4], bf[4];
#pragma unroll
      for (int mf = 0; mf < 4; ++mf)
        af[mf] = *(const short8*)(Atile + (wr * 64 + mf * 16 + lr) * 64 +
                                  ks * 32 + ls * 8);
#pragma unroll
      for (int nf = 0; nf < 4; ++nf)
        bf[nf] = *(const short8*)(Btile + (wc * 64 + nf * 16 + lr) * 64 +
                                  ks * 32 + ls * 8);
#pragma unroll
      for (int mf = 0; mf < 4; ++mf)
#pragma unroll
        for (int nf = 0; nf < 4; ++nf)
          acc[mf][nf] = mfma_bf16(af[mf], bf[nf], acc[mf][nf]);
    }
    __syncthreads();
  }

#pragma unroll
  for (int mf = 0; mf < 4; ++mf)
#pragma unroll
    for (int nf = 0; nf < 4; ++nf)
#pragma unroll
      for (int r = 0; r < 4; ++r) {
        int m = m0 + wr * 64 + mf * 16 + ls * 4 + r;
        int c = c0 + wc * 64 + nf * 16 + lr;
        float v = acc[mf][nf][r];
        if (z == 2) {
          Vf[(size_t)m * 512 + c] = v;
        } else {
          int b = m >> 10, n = m & 1023, h = c >> 6, dh = c & 63;
          size_t idx = ((size_t)(b * 8 + h) * 1024 + n) * 64 + dh;
          (z == 0 ? Qb : Kb)[idx] = f2bf(v);
        }
      }
}

// ---------------------------------------------------------------------------
// Transpose: Vf f32 [B,N,512] -> Vt bf16 [B,H,64,N]  (per-head [DH,N])
// ---------------------------------------------------------------------------
__global__ __launch_bounds__(256) void k_transpose_v(
    const float* __restrict__ Vf, unsigned short* __restrict__ Vt) {
  __shared__ unsigned short tile[64 * 66];
  const int bh = blockIdx.y;
  const int b = bh >> 3, h = bh & 7;
  const int n0 = blockIdx.x * 64;
  const int t = threadIdx.x;
  {
    int n = t >> 2, dh0 = (t & 3) * 16;
    const float* src = Vf + ((size_t)b * 1024 + n0 + n) * 512 + h * 64 + dh0;
    unsigned short* dst = tile + n * 66 + dh0;
#pragma unroll
    for (int j = 0; j < 16; j += 4) {
      float4 v = *(const float4*)(src + j);
      dst[j + 0] = f2bf(v.x); dst[j + 1] = f2bf(v.y);
      dst[j + 2] = f2bf(v.z); dst[j + 3] = f2bf(v.w);
    }
  }
  __syncthreads();
#pragma unroll
  for (int it = 0; it < 2; ++it) {
    int dh = (t >> 3) + it * 32, n8 = (t & 7) * 8;
    ushort8 o;
#pragma unroll
    for (int j = 0; j < 8; ++j) o[j] = tile[(n8 + j) * 66 + dh];
    *(ushort8*)(Vt + ((size_t)(bh * 64 + dh)) * 1024 + n0 + n8) = o;
  }
}

// ---------------------------------------------------------------------------
// k_scores: P = exp(QK^T * scale) (unnormalized; |s*scale| < ~1 so no
// max-subtract needed), masked (s==0 -> 0). Writes P bf16 [32][1024][1024]
// with per-128B-block XOR swizzle (byte ^= (n&7)<<4) so k_pv's gload_lds +
// swz ds_read is bank-conflict-free. Row sums -> lsum_g f32 [32][1024].
// ---------------------------------------------------------------------------
__global__ __launch_bounds__(256) void k_scores(
    const unsigned short* __restrict__ Qb,
    const unsigned short* __restrict__ Kb,
    unsigned short* __restrict__ Pmat, float* __restrict__ lsum_g) {
  __shared__ char lds[8192 + 4 * 16 * 144];
  char* kbuf = lds;
  const int bh = blockIdx.y;
  const int q0 = blockIdx.x * 64;
  const int t = threadIdx.x;
  const int w = t >> 6, l = t & 63, lr = l & 15, ls = l >> 4;
  char* pbuf = lds + 8192 + w * (16 * 144);

  const float sclog2e = 0.0637587160f;   // (512^-0.5) * log2(e)

  short8 qa[2];
  {
    const unsigned short* Qg =
        Qb + ((size_t)bh * 1024 + q0 + w * 16 + lr) * 64 + ls * 8;
    qa[0] = *(const short8*)(Qg);
    qa[1] = *(const short8*)(Qg + 32);
  }

  const unsigned short* Kg = Kb + (size_t)bh * 1024 * 64;
  char* Pg = (char*)(Pmat + (size_t)bh * 1024 * 1024);

  float lacc[4] = {0.f, 0.f, 0.f, 0.f};

  for (int kc = 0; kc < 16; ++kc) {
    {
      int row = t >> 3;
      int c8  = (t & 7) * 8;
#pragma unroll
      for (int it = 0; it < 2; ++it) {
        int rr = row + it * 32;
        int4 kv = *(const int4*)(Kg + (size_t)(kc * 64 + rr) * 64 + c8);
        *(int4*)(kbuf + swz(rr, c8 * 2)) = kv;
      }
    }
    __syncthreads();

    // S = Q K^T
    f32x4 s[4] = {};
#pragma unroll
    for (int kk = 0; kk < 2; ++kk) {
#pragma unroll
      for (int nt = 0; nt < 4; ++nt) {
        short8 bk = *(const short8*)(kbuf + swz(nt * 16 + lr, kk * 64 + ls * 16));
        s[nt] = mfma_bf16(qa[kk], bk, s[nt]);
      }
    }

    // p = exp(s*scale), masked; accumulate row sums; stage to pbuf
#pragma unroll
    for (int nt = 0; nt < 4; ++nt)
#pragma unroll
      for (int r = 0; r < 4; ++r) {
        float sv = s[nt][r];
        float pv = (sv == 0.f) ? 0.f : exp2f(sv * sclog2e);
        lacc[r] += pv;
        *(unsigned short*)(pbuf + (ls * 4 + r) * 144 + (nt * 16 + lr) * 2) =
            f2bf(pv);
      }

    // vectorized global write of this 64x64 P tile (swizzled layout).
    // Full tile per wave = 16 rows x 128B; 64 lanes x 16B covers half,
    // so TWO chunks per lane (c2 and c2+4).  [round-5 fix]
    {
      int r2 = l & 15;
      int n  = q0 + w * 16 + r2;
#pragma unroll
      for (int half = 0; half < 2; ++half) {
        int c2   = (l >> 4) + half * 4;    // 0..7
        ushort8 pv8 = *(const ushort8*)(pbuf + r2 * 144 + c2 * 16);
        int colb = kc * 128 + c2 * 16;
        *(ushort8*)(Pg + (size_t)n * 2048 + (colb ^ ((n & 7) << 4))) = pv8;
      }
    }
    __syncthreads();
  }

  // one reduction at the end: sum over the 16 lr lanes
#pragma unroll
  for (int r = 0; r < 4; ++r) {
#pragma unroll
    for (int off = 1; off < 16; off <<= 1)
      lacc[r] += __shfl_xor(lacc[r], off, 64);
  }
  if (lr == 0) {
#pragma unroll
    for (int r = 0; r < 4; ++r)
      lsum_g[(size_t)bh * 1024 + q0 + w * 16 + ls * 4 + r] = lacc[r];
  }
}

// ---------------------------------------------------------------------------
// k_pv: V1[n, h*64+dh] = (1/l[n]) * sum_m P[n,m] * Vt[h][dh][m].
// A = P (pre-swizzled global, gload_lds linear, swz ds_read).
// B = Vt (reg-staged, swz ds_write/ds_read). 64 n-rows per block, 4 waves.
// ---------------------------------------------------------------------------
__global__ __launch_bounds__(256) void k_pv(
    const unsigned short* __restrict__ Pmat,
    const unsigned short* __restrict__ Vt,
    const float* __restrict__ lsum_g, float* __restrict__ V1) {
  __shared__ __align__(16) char Atile[8192];
  __shared__ __align__(16) char vbuf[8192];
  const int head = blockIdx.y;
  const int n0 = blockIdx.x * 64;
  const int t = threadIdx.x;
  const int w = t >> 6, l = t & 63, lr = l & 15, ls = l >> 4;
  const int srow = l >> 3, scol8 = (l & 7) * 8;

  const char* Pg = (const char*)(Pmat + (size_t)head * 1024 * 1024);
  const unsigned short* Vg = Vt + (size_t)head * 64 * 1024;

  f32x4 acc[4] = {};

  for (int kc = 0; kc < 16; ++kc) {
    // A: 64x64 P chunk, linear copy (content already swizzled)
#pragma unroll
    for (int j = 0; j < 2; ++j) {
      int ch  = w * 2 + j;
      int row = ch * 8 + srow;
      gload_lds16(Pg + (size_t)(n0 + row) * 2048 + kc * 128 + scol8 * 2,
                  Atile + ch * 1024);
    }
    // B: Vt chunk [64 dh][64 m], reg round-trip with swizzled ds_write
    {
      int row = t >> 3;
      int c8  = (t & 7) * 8;
#pragma unroll
      for (int it = 0; it < 2; ++it) {
        int rr = row + it * 32;
        int4 vv = *(const int4*)(Vg + (size_t)rr * 1024 + kc * 64 + c8);
        *(int4*)(vbuf + swz(rr, c8 * 2)) = vv;
      }
    }
    __syncthreads();
#pragma unroll
    for (int ks = 0; ks < 2; ++ks) {
      short8 af = *(const short8*)(Atile + swz(w * 16 + lr, ks * 64 + ls * 16));
#pragma unroll
      for (int nf = 0; nf < 4; ++nf) {
        short8 bf = *(const short8*)(vbuf + swz(nf * 16 + lr, ks * 64 + ls * 16));
        acc[nf] = mfma_bf16(af, bf, acc[nf]);
      }
    }
    __syncthreads();
  }

  const int b = head >> 3, h = head & 7;
#pragma unroll
  for (int r = 0; r < 4; ++r) {
    int n = n0 + w * 16 + ls * 4 + r;
    float lv = lsum_g[(size_t)head * 1024 + n];
    float rinv = (lv > 0.f) ? 1.f / lv : 0.f;
#pragma unroll
    for (int nf = 0; nf < 4; ++nf)
      V1[((size_t)b * 1024 + n) * 512 + h * 64 + nf * 16 + lr] =
          acc[nf][r] * rinv;
  }
}

// ---------------------------------------------------------------------------
// Fallback fused flash attention (used only if workspace < 103MB)
// ---------------------------------------------------------------------------
__global__ __launch_bounds__(256) void k_attn(
    const unsigned short* __restrict__ Qb,
    const unsigned short* __restrict__ Kb,
    const unsigned short* __restrict__ Vt,
    float* __restrict__ V1) {
  __shared__ char lds[8192 + 8192 + 4 * 16 * 144];
  char* kbuf = lds;
  char* vbuf = lds + 8192;
  const int bh = blockIdx.y;
  const int q0 = blockIdx.x * 64;
  const int t = threadIdx.x;
  const int w = t >> 6, l = t & 63, lr = l & 15, ls = l >> 4;
  char* pbuf = lds + 16384 + w * (16 * 144);

  const float scale = 0.044194173824159216f;

  short8 qa[2];
  {
    const unsigned short* Qg =
        Qb + ((size_t)bh * 1024 + q0 + w * 16 + lr) * 64 + ls * 8;
    qa[0] = *(const short8*)(Qg);
    qa[1] = *(const short8*)(Qg + 32);
  }

  f32x4 O[4] = {};
  float mrow[4], lrow[4];
#pragma unroll
  for (int r = 0; r < 4; ++r) { mrow[r] = -INFINITY; lrow[r] = 0.f; }

  const unsigned short* Kg = Kb + (size_t)bh * 1024 * 64;
  const unsigned short* Vg = Vt + (size_t)bh * 64 * 1024;

  for (int kc = 0; kc < 16; ++kc) {
    {
      int row = t >> 3;
      int c8  = (t & 7) * 8;
#pragma unroll
      for (int it = 0; it < 2; ++it) {
        int rr = row + it * 32;
        int4 kv = *(const int4*)(Kg + (size_t)(kc * 64 + rr) * 64 + c8);
        *(int4*)(kbuf + swz(rr, c8 * 2)) = kv;
        int4 vv = *(const int4*)(Vg + (size_t)rr * 1024 + kc * 64 + c8);
        *(int4*)(vbuf + swz(rr, c8 * 2)) = vv;
      }
    }
    __syncthreads();

    f32x4 s[4] = {};
#pragma unroll
    for (int kk = 0; kk < 2; ++kk) {
#pragma unroll
      for (int nt = 0; nt < 4; ++nt) {
        short8 bk = *(const short8*)(kbuf + swz(nt * 16 + lr, kk * 64 + ls * 16));
        s[nt] = mfma_bf16(qa[kk], bk, s[nt]);
      }
    }

    float p[4][4];
    float cmax[4];
#pragma unroll
    for (int r = 0; r < 4; ++r) cmax[r] = -INFINITY;
#pragma unroll
    for (int nt = 0; nt < 4; ++nt)
#pragma unroll
      for (int r = 0; r < 4; ++r) {
        float sv = s[nt][r];
        p[nt][r] = (sv == 0.f) ? -INFINITY : sv * scale;
        cmax[r] = fmaxf(cmax[r], p[nt][r]);
      }
#pragma unroll
    for (int r = 0; r < 4; ++r)
#pragma unroll
      for (int off = 1; off < 16; off <<= 1)
        cmax[r] = fmaxf(cmax[r], __shfl_xor(cmax[r], off, 64));

    float alpha[4];
#pragma unroll
    for (int r = 0; r < 4; ++r) {
      float mnew = fmaxf(mrow[r], cmax[r]);
      alpha[r] = (mnew == -INFINITY) ? 1.f : exp2f((mrow[r] - mnew) * LOG2E);
      mrow[r] = mnew;
    }
    float lsum[4] = {0.f, 0.f, 0.f, 0.f};
#pragma unroll
    for (int nt = 0; nt < 4; ++nt)
#pragma unroll
      for (int r = 0; r < 4; ++r) {
        float pv = (p[nt][r] == -INFINITY)
                       ? 0.f
                       : exp2f((p[nt][r] - mrow[r]) * LOG2E);
        p[nt][r] = pv;
        lsum[r] += pv;
      }
#pragma unroll
    for (int r = 0; r < 4; ++r) {
#pragma unroll
      for (int off = 1; off < 16; off <<= 1)
        lsum[r] += __shfl_xor(lsum[r], off, 64);
      lrow[r] = lrow[r] * alpha[r] + lsum[r];
    }
#pragma unroll
    for (int dt = 0; dt < 4; ++dt)
#pragma unroll
      for (int r = 0; r < 4; ++r) O[dt][r] *= alpha[r];

#pragma unroll
    for (int nt = 0; nt < 4; ++nt)
#pragma unroll
      for (int r = 0; r < 4; ++r)
        *(unsigned short*)(pbuf + (ls * 4 + r) * 144 + (nt * 16 + lr) * 2) =
            f2bf(p[nt][r]);

#pragma unroll
    for (int kk = 0; kk < 2; ++kk) {
      short8 pa = *(const short8*)(pbuf + lr * 144 + kk * 64 + ls * 16);
#pragma unroll
      for (int dt = 0; dt < 4; ++dt) {
        short8 bv = *(const short8*)(vbuf + swz(dt * 16 + lr, kk * 64 + ls * 16));
        O[dt] = mfma_bf16(pa, bv, O[dt]);
      }
    }
    __syncthreads();
  }

  float rinv[4];
#pragma unroll
  for (int r = 0; r < 4; ++r) rinv[r] = (lrow[r] > 0.f) ? 1.f / lrow[r] : 0.f;
  const int b = bh >> 3, h = bh & 7;
#pragma unroll
  for (int dt = 0; dt < 4; ++dt)
#pragma unroll
    for (int r = 0; r < 4; ++r) {
      int n = q0 + w * 16 + ls * 4 + r;
      int c = h * 64 + dt * 16 + lr;
      V1[((size_t)b * 1024 + n) * 512 + c] = O[dt][r] * rinv[r];
    }
}

// ---------------------------------------------------------------------------
// LayerNorm over C=512 of (V1 + Vf)
// ---------------------------------------------------------------------------
__global__ __launch_bounds__(256) void k_ln(
    const float* __restrict__ V1, const float* __restrict__ Vf_in,
    const float* __restrict__ gamma, const float* __restrict__ beta,
    float* __restrict__ outp) {
  const int row = blockIdx.x;
  const int t = threadIdx.x;
  const float* a = V1 + (size_t)row * 512;
  const float* b = Vf_in + (size_t)row * 512;
  float x0 = a[t] + b[t];
  float x1 = a[t + 256] + b[t + 256];
  float s  = x0 + x1;
  float sq = x0 * x0 + x1 * x1;
#pragma unroll
  for (int off = 32; off >= 1; off >>= 1) {
    s  += __shfl_down(s, off, 64);
    sq += __shfl_down(sq, off, 64);
  }
  __shared__ float red[8];
  int w = t >> 6, l = t & 63;
  if (l == 0) { red[w] = s; red[w + 4] = sq; }
  __syncthreads();
  s  = red[0] + red[1] + red[2] + red[3];
  sq = red[4] + red[5] + red[6] + red[7];
  float mu   = s * (1.f / 512.f);
  float var  = sq * (1.f / 512.f) - mu * mu;
  float rstd = rsqrtf(var + 1e-5f);
  float y0 = (x0 - mu) * rstd * gamma[t] + beta[t];
  float y1 = (x1 - mu) * rstd * gamma[t + 256] + beta[t + 256];
  outp[(size_t)row * 512 + t] = y0;
  outp[(size_t)row * 512 + t + 256] = y1;
}

// ---------------------------------------------------------------------------
extern "C" void kernel_launch(void* const* d_in, const int* in_sizes, int n_in,
                              void* d_out, int out_size, void* d_ws,
                              size_t ws_size, hipStream_t stream) {
  const float* x1    = (const float*)d_in[0];
  const float* x2    = (const float*)d_in[1];
  const float* Wq    = (const float*)d_in[2];
  const float* Wk    = (const float*)d_in[3];
  const float* Wv    = (const float*)d_in[4];
  const float* gamma = (const float*)d_in[5];
  const float* beta  = (const float*)d_in[6];
  float* out = (float*)d_out;
  char* ws = (char*)d_ws;

  const size_t MB = 1u << 20;
  unsigned short* xb  = (unsigned short*)(ws);                 // 8 MB
  unsigned short* Wqb = (unsigned short*)(ws + 8 * MB);        // 0.5 MB
  unsigned short* Wkb = (unsigned short*)(ws + 8 * MB + 512 * 1024);
  unsigned short* Wvb = (unsigned short*)(ws + 9 * MB);        // 1 MB
  unsigned short* Qb  = (unsigned short*)(ws + 10 * MB);       // 4 MB
  unsigned short* Kb  = (unsigned short*)(ws + 14 * MB);       // 4 MB
  unsigned short* Vt  = (unsigned short*)(ws + 18 * MB);       // 4 MB
  float*          Vf  = (float*)(ws + 22 * MB);                // 8 MB
  float*          V1  = (float*)(ws + 30 * MB);                // 8 MB
  float*          lsm = (float*)(ws + 38 * MB);                // 128 KB
  unsigned short* Pm  = (unsigned short*)(ws + 39 * MB);       // 64 MB

  const bool bigws = ws_size >= (size_t)103 * MB;

  k_convert_x<<<2048, 256, 0, stream>>>(x1, x2, xb);
  k_convert<<<128, 256, 0, stream>>>(Wq, Wqb, 32768);
  k_convert<<<128, 256, 0, stream>>>(Wk, Wkb, 32768);
  k_convert<<<256, 256, 0, stream>>>(Wv, Wvb, 65536);

  k_proj<<<384, 256, 0, stream>>>(xb, Wqb, Wkb, Wvb, Qb, Kb, Vf);
  k_transpose_v<<<dim3(16, 32), 256, 0, stream>>>(Vf, Vt);

  if (bigws) {
    k_scores<<<dim3(16, 32), 256, 0, stream>>>(Qb, Kb, Pm, lsm);
    for (int layer = 0; layer < 3; ++layer) {
      k_pv<<<dim3(16, 32), 256, 0, stream>>>(Pm, Vt, lsm, V1);
      k_ln<<<4096, 256, 0, stream>>>(V1, Vf, gamma, beta,
                                     (layer == 2) ? out : Vf);
      if (layer < 2) k_transpose_v<<<dim3(16, 32), 256, 0, stream>>>(Vf, Vt);
    }
  } else {
    for (int layer = 0; layer < 3; ++layer) {
      k_attn<<<dim3(16, 32), 256, 0, stream>>>(Qb, Kb, Vt, V1);
      k_ln<<<4096, 256, 0, stream>>>(V1, Vf, gamma, beta,
                                     (layer == 2) ? out : Vf);
      if (layer < 2) k_transpose_v<<<dim3(16, 32), 256, 0, stream>>>(Vf, Vt);
    }
  }
}